// Round 1
// baseline (126.346 us; speedup 1.0000x reference)
//
#include <hip/hip_runtime.h>

#define NB 512
#define SLOTS 32
#define D 1024
#define D4 256           // D/4 (float4 per row)
#define TC 16            // tokens per chunk
#define MAX_TOK 512
#define TAU_INV 10.0f

__global__ __launch_bounds__(256, 2)
void cam_read_kernel(const float* __restrict__ query,    // [NT][D]
                     const int*   __restrict__ tids,     // [NT]
                     const float* __restrict__ skeys,    // [NB*SLOTS][D]
                     const float* __restrict__ svals,    // [NB*SLOTS][D]
                     const int*   __restrict__ stids,    // [NB*SLOTS]
                     const float* __restrict__ centroid, // [NB][D]
                     float*       __restrict__ out,      // [NT][D]
                     int n_tokens)
{
    const int bucket = blockIdx.x;
    const int tidx   = threadIdx.x;      // 0..255
    const int lane   = tidx & 63;
    const int wid    = tidx >> 6;        // 0..3

    __shared__ float s_anchor[D];
    __shared__ float s_uq[TC][D];
    __shared__ float s_scores[TC][SLOTS];
    __shared__ float s_probs[TC][SLOTS];
    __shared__ int   s_toklist[MAX_TOK];
    __shared__ int   s_toktid[TC];
    __shared__ int   s_count;

    // ---- load anchor row (one float4 per thread) ----
    ((float4*)s_anchor)[tidx] = ((const float4*)centroid)[bucket * D4 + tidx];

    // ---- wave 0 scans tids, ordered ballot-compaction into token list ----
    if (wid == 0) {
        int cnt = 0;
        for (int base = 0; base < n_tokens; base += 64) {
            int idx = base + lane;
            bool m = false;
            if (idx < n_tokens) {
                int tv = tids[idx];
                m = ((tv & (NB - 1)) == bucket);
            }
            unsigned long long mask = __ballot(m);
            if (m) {
                int pos = cnt + __popcll(mask & ((1ull << lane) - 1ull));
                if (pos < MAX_TOK) s_toklist[pos] = idx;
            }
            cnt += __popcll(mask);
        }
        if (lane == 0) s_count = (cnt > MAX_TOK) ? MAX_TOK : cnt;
    }
    __syncthreads();

    const int count = s_count;
    if (count == 0) return;

    for (int c0 = 0; c0 < count; c0 += TC) {
        const int nt = min(TC, count - c0);

        // ---- unified queries: wave w handles tokens t = w, w+4, ... ----
        for (int t = wid; t < nt; t += 4) {
            const int tok = s_toklist[c0 + t];
            const float4* q4 = (const float4*)(query + (size_t)tok * D);
            float4 qv[4];
            float ss = 0.f;
            #pragma unroll
            for (int j = 0; j < 4; ++j) {
                qv[j] = q4[lane + 64 * j];
                ss += qv[j].x*qv[j].x + qv[j].y*qv[j].y + qv[j].z*qv[j].z + qv[j].w*qv[j].w;
            }
            #pragma unroll
            for (int off = 32; off >= 1; off >>= 1) ss += __shfl_xor(ss, off);
            const float qn = 0.5f / fmaxf(sqrtf(ss), 1e-12f);   // folds ALPHA=0.5

            float4 uv[4];
            float ss2 = 0.f;
            #pragma unroll
            for (int j = 0; j < 4; ++j) {
                float4 av = ((const float4*)s_anchor)[lane + 64 * j];
                uv[j].x = qv[j].x * qn + 0.5f * av.x;
                uv[j].y = qv[j].y * qn + 0.5f * av.y;
                uv[j].z = qv[j].z * qn + 0.5f * av.z;
                uv[j].w = qv[j].w * qn + 0.5f * av.w;
                ss2 += uv[j].x*uv[j].x + uv[j].y*uv[j].y + uv[j].z*uv[j].z + uv[j].w*uv[j].w;
            }
            #pragma unroll
            for (int off = 32; off >= 1; off >>= 1) ss2 += __shfl_xor(ss2, off);
            const float un = 1.0f / fmaxf(sqrtf(ss2), 1e-12f);
            #pragma unroll
            for (int j = 0; j < 4; ++j) {
                float4 w4 = make_float4(uv[j].x*un, uv[j].y*un, uv[j].z*un, uv[j].w*un);
                ((float4*)s_uq[t])[lane + 64 * j] = w4;
            }
            if (lane == 0) s_toktid[t] = tids[tok];
        }
        __syncthreads();

        // ---- scores: wave w owns slots w*8 .. w*8+7 ----
        for (int s8 = 0; s8 < 8; ++s8) {
            const int s = wid * 8 + s8;
            const float4* k4 = (const float4*)(skeys + ((size_t)bucket * SLOTS + s) * D);
            float4 kv[4];
            #pragma unroll
            for (int j = 0; j < 4; ++j) kv[j] = k4[lane + 64 * j];
            for (int t = 0; t < nt; ++t) {
                const float4* u4 = (const float4*)s_uq[t];
                float acc = 0.f;
                #pragma unroll
                for (int j = 0; j < 4; ++j) {
                    float4 uvv = u4[lane + 64 * j];
                    acc += kv[j].x*uvv.x + kv[j].y*uvv.y + kv[j].z*uvv.z + kv[j].w*uvv.w;
                }
                #pragma unroll
                for (int off = 32; off >= 1; off >>= 1) acc += __shfl_xor(acc, off);
                if (lane == 0) s_scores[t][s] = acc;
            }
        }
        __syncthreads();

        // ---- softmax + hard-match per token (32 lanes each) ----
        for (int t = wid; t < nt; t += 4) {
            if (lane < 32) {
                const int s = lane;
                const float sc = s_scores[t][s];
                const int match = (stids[bucket * SLOTS + s] == s_toktid[t]) ? 1 : 0;
                float mx = sc;
                #pragma unroll
                for (int off = 16; off >= 1; off >>= 1) mx = fmaxf(mx, __shfl_xor(mx, off));
                const float e = expf((sc - mx) * TAU_INV);
                float es = e;
                int   ms = match;
                #pragma unroll
                for (int off = 16; off >= 1; off >>= 1) {
                    es += __shfl_xor(es, off);
                    ms += __shfl_xor(ms, off);
                }
                float p;
                if (ms > 0) p = (float)match / ((float)ms + 1e-9f);
                else        p = e / es;
                s_probs[t][s] = p;
            }
        }
        __syncthreads();

        // ---- values: each thread owns float4 column tidx; acc in registers ----
        float4 acc[TC];
        #pragma unroll
        for (int t = 0; t < TC; ++t) acc[t] = make_float4(0.f, 0.f, 0.f, 0.f);

        for (int s = 0; s < SLOTS; ++s) {
            float4 v = ((const float4*)(svals + ((size_t)bucket * SLOTS + s) * D))[tidx];
            #pragma unroll
            for (int t = 0; t < TC; ++t) {
                if (t < nt) {
                    float p = s_probs[t][s];
                    acc[t].x += p * v.x;
                    acc[t].y += p * v.y;
                    acc[t].z += p * v.z;
                    acc[t].w += p * v.w;
                }
            }
        }
        #pragma unroll
        for (int t = 0; t < TC; ++t) {
            if (t < nt) {
                const int tok = s_toklist[c0 + t];
                ((float4*)(out + (size_t)tok * D))[tidx] = acc[t];
            }
        }
        __syncthreads();   // LDS reused next chunk
    }
}

extern "C" void kernel_launch(void* const* d_in, const int* in_sizes, int n_in,
                              void* d_out, int out_size, void* d_ws, size_t ws_size,
                              hipStream_t stream) {
    const float* query    = (const float*)d_in[0];
    const int*   tids     = (const int*)  d_in[1];
    const float* skeys    = (const float*)d_in[2];
    const float* svals    = (const float*)d_in[3];
    const int*   stids    = (const int*)  d_in[4];
    const float* centroid = (const float*)d_in[5];
    float* out = (float*)d_out;
    const int n_tokens = in_sizes[1];

    cam_read_kernel<<<NB, 256, 0, stream>>>(query, tids, skeys, svals, stids,
                                            centroid, out, n_tokens);
}